// Round 6
// baseline (184.563 us; speedup 1.0000x reference)
//
#include <hip/hip_runtime.h>

// 1-NN (squared-L2 argmin over 500000x256 f32 keys) + dot(values[idx], query).
// Memory-bound: 512 MB of keys stream once. R6: fuse finish into the argmin
// kernel via last-block-done with SCOPED atomics (no NT loads, no per-block
// __threadfence -- R2's two mistakes). Strided sliding-window mapping kept
// from R5. Counter needs a 4-byte memset (0xAA poison breaks mod-GRID trick).

#define D 256
#define D4 (D / 4)            // 64 float4 per row == one wave-wide 1 KB load
#define BLOCK 256
#define GRID 2048             // 8 blocks/CU, 32 waves/CU
#define WPB (BLOCK / 64)
#define NWAV (GRID * WPB)     // 8192 waves

// Monotonic float->uint map (inputs are finite gaussians, no NaN).
__device__ __forceinline__ unsigned int fkey(float f) {
    unsigned int u = __float_as_uint(f);
    return (u & 0x80000000u) ? ~u : (u | 0x80000000u);
}

__device__ __forceinline__ float rowpart(float4 a, float4 qm2) {
    return a.x * (a.x + qm2.x) + a.y * (a.y + qm2.y)
         + a.z * (a.z + qm2.z) + a.w * (a.w + qm2.w);
}

__global__ __launch_bounds__(BLOCK) void nn_fused_kernel(
    const float* __restrict__ query,
    const float* __restrict__ keys,
    const float* __restrict__ values,
    unsigned long long* __restrict__ blockBest,  // d_ws[0..16K)
    unsigned int* __restrict__ counter,          // d_ws+16K, memset 0 per call
    float* __restrict__ out,
    int N)
{
    const int lane  = threadIdx.x & 63;
    const int wib   = threadIdx.x >> 6;
    const int gwave = blockIdx.x * WPB + wib;

    const float4 q = reinterpret_cast<const float4*>(query)[lane];
    const float4 qm2 = make_float4(-2.f * q.x, -2.f * q.y, -2.f * q.z, -2.f * q.w);

    unsigned long long myBest = 0xFFFFFFFFFFFFFFFFull;  // smaller == better

    const float4* __restrict__ k4 = reinterpret_cast<const float4*>(keys);

    // Strided sweep: at any iteration the 8192 waves collectively read one
    // contiguous 16 MB window sliding through keys (R5, +3.5%).
    for (int r = gwave * 2; r + 1 < N; r += 2 * NWAV) {
        float4 a = k4[(size_t)(r + 0) * D4 + lane];
        float4 b = k4[(size_t)(r + 1) * D4 + lane];
        float pa = rowpart(a, qm2);
        float pb = rowpart(b, qm2);
        #pragma unroll
        for (int off = 32; off; off >>= 1) {
            pa += __shfl_down(pa, off, 64);
            pb += __shfl_down(pb, off, 64);
        }
        if (lane == 0) {
            unsigned long long ka = ((unsigned long long)fkey(pa) << 32) | (unsigned int)(r + 0);
            unsigned long long kb = ((unsigned long long)fkey(pb) << 32) | (unsigned int)(r + 1);
            ka = min(ka, kb);
            if (ka < myBest) myBest = ka;
        }
    }
    if (N & 1) {   // dead for N=500000, kept for safety
        int rl = N - 1;
        if (((rl >> 1) % NWAV) == gwave) {
            float4 a = k4[(size_t)rl * D4 + lane];
            float pa = rowpart(a, qm2);
            #pragma unroll
            for (int off = 32; off; off >>= 1) pa += __shfl_down(pa, off, 64);
            if (lane == 0) {
                unsigned long long ka = ((unsigned long long)fkey(pa) << 32) | (unsigned int)rl;
                if (ka < myBest) myBest = ka;
            }
        }
    }

    // Block reduce in LDS; thread0 publishes (relaxed store + release RMW).
    __shared__ unsigned long long s_best[WPB];
    __shared__ bool amLast;
    if (lane == 0) s_best[wib] = myBest;
    __syncthreads();
    if (threadIdx.x == 0) {
        unsigned long long m = s_best[0];
        #pragma unroll
        for (int i = 1; i < WPB; ++i) m = min(m, s_best[i]);
        __hip_atomic_store(&blockBest[blockIdx.x], m,
                           __ATOMIC_RELAXED, __HIP_MEMORY_SCOPE_AGENT);
        unsigned int old = __hip_atomic_fetch_add(counter, 1u,
                           __ATOMIC_ACQ_REL, __HIP_MEMORY_SCOPE_AGENT);
        amLast = (old == GRID - 1);   // exactly one block, after all stores
    }
    __syncthreads();
    if (!amLast) return;

    // Winner block: reduce the 2048 published bests, then values[idx]@query.
    unsigned long long m = 0xFFFFFFFFFFFFFFFFull;
    for (int i = threadIdx.x; i < GRID; i += BLOCK)
        m = min(m, __hip_atomic_load(&blockBest[i],
                   __ATOMIC_RELAXED, __HIP_MEMORY_SCOPE_AGENT));
    #pragma unroll
    for (int off = 32; off; off >>= 1)
        m = min(m, __shfl_down(m, off, 64));

    __shared__ unsigned long long s_fin[WPB];
    __shared__ int s_idx;
    if (lane == 0) s_fin[wib] = m;
    __syncthreads();
    if (threadIdx.x == 0) {
        unsigned long long mm = s_fin[0];
        #pragma unroll
        for (int i = 1; i < WPB; ++i) mm = min(mm, s_fin[i]);
        s_idx = (int)(mm & 0xFFFFFFFFull);
    }
    __syncthreads();

    if (threadIdx.x < 64) {
        const float4 v = reinterpret_cast<const float4*>(values)[(size_t)s_idx * D4 + lane];
        float d = v.x * q.x + v.y * q.y + v.z * q.z + v.w * q.w;
        #pragma unroll
        for (int off = 32; off; off >>= 1) d += __shfl_down(d, off, 64);
        if (lane == 0) out[0] = d;
    }
}

extern "C" void kernel_launch(void* const* d_in, const int* in_sizes, int n_in,
                              void* d_out, int out_size, void* d_ws, size_t ws_size,
                              hipStream_t stream) {
    const float* query  = (const float*)d_in[0];
    const float* keys   = (const float*)d_in[1];
    const float* values = (const float*)d_in[2];
    const int N = in_sizes[1] / D;

    unsigned long long* blockBest = (unsigned long long*)d_ws;      // 16 KB
    unsigned int* counter = (unsigned int*)((char*)d_ws + GRID * 8);

    // Counter must start at 0 each call (0xAA poison + replays otherwise
    // break the last-block test). 4-byte memset, capture-safe.
    hipMemsetAsync(counter, 0, sizeof(unsigned int), stream);

    nn_fused_kernel<<<GRID, BLOCK, 0, stream>>>(query, keys, values, blockBest,
                                                counter, (float*)d_out, N);
}

// Round 7
// 94.293 us; speedup vs baseline: 1.9573x; 1.9573x over previous
//
#include <hip/hip_runtime.h>

// 1-NN (squared-L2 argmin over 500000x256 f32 keys) + dot(values[idx], query).
// Memory-bound: 512 MB of keys stream once; floor ~= 512MB / ~6.3 TB/s.
// R7 = R5 argmin (proven 93.4 us: strided sliding-window, 2 rows/iter, plain
// loads, one plain store per block) + finish kernel slimmed to a single wave
// (no LDS, no __syncthreads, vectorized 16B loads).
// Anti-lessons (measured): NT loads = ~5x slower streams (R2); per-block
// ordered atomics/fences = +91 us serialized tail (R6). Kernel boundary is
// the cheapest device-wide release.

#define D 256
#define D4 (D / 4)            // 64 float4 per row == one wave-wide 1 KB load
#define BLOCK 256
#define GRID 2048             // 8 blocks/CU, 32 waves/CU (occupancy cap)
#define WPB (BLOCK / 64)
#define NWAV (GRID * WPB)     // 8192 waves

// Monotonic float->uint map (inputs are finite gaussians, no NaN).
__device__ __forceinline__ unsigned int fkey(float f) {
    unsigned int u = __float_as_uint(f);
    return (u & 0x80000000u) ? ~u : (u | 0x80000000u);
}

__device__ __forceinline__ float rowpart(float4 a, float4 qm2) {
    return a.x * (a.x + qm2.x) + a.y * (a.y + qm2.y)
         + a.z * (a.z + qm2.z) + a.w * (a.w + qm2.w);
}

__global__ __launch_bounds__(BLOCK) void nn_argmin_kernel(
    const float* __restrict__ query,
    const float* __restrict__ keys,
    unsigned long long* __restrict__ blockBest,  // d_ws, GRID entries
    int N)
{
    const int lane  = threadIdx.x & 63;
    const int wib   = threadIdx.x >> 6;
    const int gwave = blockIdx.x * WPB + wib;

    const float4 q = reinterpret_cast<const float4*>(query)[lane];
    const float4 qm2 = make_float4(-2.f * q.x, -2.f * q.y, -2.f * q.z, -2.f * q.w);

    unsigned long long myBest = 0xFFFFFFFFFFFFFFFFull;  // smaller == better

    const float4* __restrict__ k4 = reinterpret_cast<const float4*>(keys);

    // Strided sweep: at any iteration the 8192 waves collectively read one
    // contiguous 16 MB window sliding through keys (R5: +3.5% vs chunked).
    for (int r = gwave * 2; r + 1 < N; r += 2 * NWAV) {
        float4 a = k4[(size_t)(r + 0) * D4 + lane];
        float4 b = k4[(size_t)(r + 1) * D4 + lane];
        float pa = rowpart(a, qm2);
        float pb = rowpart(b, qm2);
        #pragma unroll
        for (int off = 32; off; off >>= 1) {
            pa += __shfl_down(pa, off, 64);
            pb += __shfl_down(pb, off, 64);
        }
        if (lane == 0) {
            unsigned long long ka = ((unsigned long long)fkey(pa) << 32) | (unsigned int)(r + 0);
            unsigned long long kb = ((unsigned long long)fkey(pb) << 32) | (unsigned int)(r + 1);
            ka = min(ka, kb);
            if (ka < myBest) myBest = ka;
        }
    }
    if (N & 1) {   // dead for N=500000, kept for safety
        int rl = N - 1;
        if (((rl >> 1) % NWAV) == gwave) {
            float4 a = k4[(size_t)rl * D4 + lane];
            float pa = rowpart(a, qm2);
            #pragma unroll
            for (int off = 32; off; off >>= 1) pa += __shfl_down(pa, off, 64);
            if (lane == 0) {
                unsigned long long ka = ((unsigned long long)fkey(pa) << 32) | (unsigned int)rl;
                if (ka < myBest) myBest = ka;
            }
        }
    }

    // Block reduction in LDS, then ONE plain store per block (no atomics,
    // every slot overwritten every call -> no init dispatch needed).
    __shared__ unsigned long long s_best[WPB];
    if (lane == 0) s_best[wib] = myBest;
    __syncthreads();
    if (threadIdx.x == 0) {
        unsigned long long m = s_best[0];
        #pragma unroll
        for (int i = 1; i < WPB; ++i) m = min(m, s_best[i]);
        blockBest[blockIdx.x] = m;
    }
}

// Single-wave finish: min-reduce 2048 packed entries (16 KB, vectorized),
// broadcast winner index, 64-lane dot. No LDS, no __syncthreads.
__global__ __launch_bounds__(64) void nn_finish_kernel(
    const float* __restrict__ query,
    const float* __restrict__ values,
    const unsigned long long* __restrict__ blockBest,
    float* __restrict__ out)
{
    const int lane = threadIdx.x;

    typedef unsigned long long u64;
    typedef __attribute__((ext_vector_type(2))) unsigned long long u64x2;

    const u64x2* bb2 = reinterpret_cast<const u64x2*>(blockBest);
    u64 m = 0xFFFFFFFFFFFFFFFFull;
    #pragma unroll
    for (int i = 0; i < GRID / 2 / 64; ++i) {          // 16 iters, 1 KB each
        u64x2 v = bb2[i * 64 + lane];
        m = min(m, min(v.x, v.y));
    }
    #pragma unroll
    for (int off = 32; off; off >>= 1)
        m = min(m, __shfl_down(m, off, 64));
    const int idx = (int)(__shfl(m, 0, 64) & 0xFFFFFFFFull);  // broadcast

    const float4 v = reinterpret_cast<const float4*>(values)[(size_t)idx * D4 + lane];
    const float4 q = reinterpret_cast<const float4*>(query)[lane];
    float d = v.x * q.x + v.y * q.y + v.z * q.z + v.w * q.w;
    #pragma unroll
    for (int off = 32; off; off >>= 1) d += __shfl_down(d, off, 64);
    if (lane == 0) out[0] = d;
}

extern "C" void kernel_launch(void* const* d_in, const int* in_sizes, int n_in,
                              void* d_out, int out_size, void* d_ws, size_t ws_size,
                              hipStream_t stream) {
    const float* query  = (const float*)d_in[0];
    const float* keys   = (const float*)d_in[1];
    const float* values = (const float*)d_in[2];
    const int N = in_sizes[1] / D;

    unsigned long long* blockBest = (unsigned long long*)d_ws;  // 16 KB used

    nn_argmin_kernel<<<GRID, BLOCK, 0, stream>>>(query, keys, blockBest, N);
    nn_finish_kernel<<<1, 64, 0, stream>>>(query, values, blockBest,
                                           (float*)d_out);
}